// Round 1
// baseline (181.983 us; speedup 1.0000x reference)
//
#include <hip/hip_runtime.h>
#include <hip/hip_bf16.h>

// NeighborAttention on MI355X. fp32 in/out, int32 mask.
// KEY INSIGHT (R0): query = broadcast of masked neighbor-mean -> all seq
// positions share one query per (b,h). Attention collapses to GEMV-scale work.
// R6/R7 POST-MORTEM: device-wide software barriers cost ~40us EACH on MI355X.
// Mega-kernel abandoned; kernel boundaries are the cheap barrier.
// R8: 168.3us with 7 launches (scores and weighted-pool split via scp slabs).
// R9 (this round): fuse k_scores + k_wpe -> k_swp. Each block owns (b, 32-seq
// chunk); phase A accumulates the FULL 1024-d score in registers across 4
// kc-chunks (x staged in LDS, pad-260 stride), cross-half shfl_xor completes
// the dot; phase B: e=exp(score)*mask in LDS + den partial; phase C: weighted
// pool with per-wave d-chunks, x re-read L2-hot. Eliminates scp round-trip
// (10 MB), one launch (7->6), one x pass, and k_wpe's 4x cross-wave L2
// read amplification. nump goes 16 -> 32 slabs (k_xwred updated).

#define DIM  1024
#define NH   16
#define HD   64
#define BS   8
#define SEQ  1024
#define NNB  50

// workspace offsets (floats), all 16B-aligned
#define OF_P     16
#define OF_NUMP  131088
#define OF_DENP  4325392
#define OF_XW    4329488
#define OF_CTX   4460560
#define OF_OUTR  4468752

// ---------------- K1: fused neighbor-pool + q + p, one block per (h,b) -------
__global__ void k_prep(const float* __restrict__ xnb, const float* __restrict__ nm,
                       const float* __restrict__ qw, const float* __restrict__ qb,
                       const float* __restrict__ kw, float* __restrict__ p){
  int h = blockIdx.x & 15, b = blockIdx.x >> 4;
  int tid = threadIdx.x, wv = tid >> 6, ln = tid & 63;
  __shared__ float xnl[1024];
  __shared__ float qp[256];
  __shared__ float ql[64];
  {  // masked neighbor mean
    int d = tid*4;
    float4 acc = {0,0,0,0}; float wsum = 0.f;
    #pragma unroll 10
    for (int n=0; n<NNB; n++){
      float w = nm[b*NNB + n];
      float4 v = *(const float4*)(xnb + (size_t)(b*NNB + n)*DIM + d);
      acc.x += w*v.x; acc.y += w*v.y; acc.z += w*v.z; acc.w += w*v.w;
      wsum += w;
    }
    float inv = 1.f/wsum;
    acc.x*=inv; acc.y*=inv; acc.z*=inv; acc.w*=inv;
    *(float4*)(xnl + d) = acc;
  }
  __syncthreads();
  {  // q partial: lane ln -> row h*64+ln of qw, wave wv -> 256-d chunk
    const float* qrow = qw + (size_t)(h*HD + ln)*DIM + wv*256;
    const float* xrow = xnl + wv*256;
    float part = 0.f;
    #pragma unroll 16
    for (int i=0; i<64; i++){
      float4 a = *(const float4*)(qrow + i*4);
      float4 c = *(const float4*)(xrow + i*4);
      part += a.x*c.x + a.y*c.y + a.z*c.z + a.w*c.w;
    }
    qp[wv*64 + ln] = part;
  }
  __syncthreads();
  if (wv == 0){
    float qv = qp[ln] + qp[64+ln] + qp[128+ln] + qp[192+ln];
    ql[ln] = (qv + qb[h*HD + ln]) * 0.125f;
  }
  __syncthreads();
  {  // p[b,h,d] = sum_j ql[j]*kw[h*64+j,d]
    int d = tid*4;
    float4 acc = {0,0,0,0};
    #pragma unroll 8
    for (int j=0; j<HD; j++){
      float qj = ql[j];
      float4 kv = *(const float4*)(kw + (size_t)(h*HD + j)*DIM + d);
      acc.x += qj*kv.x; acc.y += qj*kv.y; acc.z += qj*kv.z; acc.w += qj*kv.w;
    }
    *(float4*)(p + (size_t)(b*NH + h)*DIM + d) = acc;
  }
}

// ---------------- K2: fused scores + exp + weighted pool --------------------
// grid (8 b, 32 sc), block 256 = 4 waves. Each block: 32 seq rows, 16 heads.
// Phase A: score[s][h] = x[b,s,:].p[b,h,:] over full 1024 d (kc loop, LDS
//   x tile 32x256 pad 260, p chunk [d][h/4]); lane ln: s=ln&31, half=ln>>5
//   covers 128 d per kc; shfl_xor(32) completes the dot.
// Phase B: e = mask * exp(score) into wlds; den partial per head.
// Phase C: wave wv -> d chunk wv*256+ln*4; 16-head accumulators; x re-read
//   from L2 (just staged, hot); writes nump slab sc.
__global__ void k_swp(const float* __restrict__ x, const float* __restrict__ p,
                      const int* __restrict__ mask,
                      float* __restrict__ nump, float* __restrict__ denp){
  int b = blockIdx.x, sc = blockIdx.y;
  int s0 = sc * 32;
  int tid = threadIdx.x, wv = tid >> 6, ln = tid & 63;
  __shared__ float4 plds[256*5];      // [d][h/4] p chunk, 20 KB
  __shared__ float  xlds[32*260];     // [s][d] 32x256 tile, pad 260 (33.3 KB)
  __shared__ float4 wlds[32*5];       // e values [s][h/4], 2.5 KB
  float* pf = (float*)plds;
  float* wf = (float*)wlds;

  int s = ln & 31, half = ln >> 5;
  float acc[4] = {0.f,0.f,0.f,0.f};
  for (int kc=0; kc<4; kc++){
    __syncthreads();                  // protect prev-iter LDS reads
    #pragma unroll
    for (int it=0; it<16; it++){      // stage p chunk: 16 h x 256 d
      int idx = it*256 + tid;
      int d = idx & 255, h = idx >> 8;
      pf[d*20 + h] = p[(size_t)(b*NH + h)*DIM + kc*256 + d];
    }
    #pragma unroll
    for (int it=0; it<8; it++){       // stage x tile 32 s x 256 d via float4
      int idx = it*256 + tid;
      int dd4 = idx & 63, ss = idx >> 6;
      float4 v = *(const float4*)(x + (size_t)(b*SEQ + s0 + ss)*DIM + kc*256 + dd4*4);
      *(float4*)(xlds + ss*260 + dd4*4) = v;
    }
    __syncthreads();
    #pragma unroll 8
    for (int dd4=0; dd4<32; dd4++){
      float4 xq = *(const float4*)(xlds + s*260 + half*128 + dd4*4);
      int dbase = (half*128 + dd4*4)*5 + wv;
      float4 p0 = plds[dbase], p1 = plds[dbase+5], p2 = plds[dbase+10], p3 = plds[dbase+15];
      acc[0] += xq.x*p0.x + xq.y*p1.x + xq.z*p2.x + xq.w*p3.x;
      acc[1] += xq.x*p0.y + xq.y*p1.y + xq.z*p2.y + xq.w*p3.y;
      acc[2] += xq.x*p0.z + xq.y*p1.z + xq.z*p2.z + xq.w*p3.z;
      acc[3] += xq.x*p0.w + xq.y*p1.w + xq.z*p2.w + xq.w*p3.w;
    }
  }
  #pragma unroll
  for (int u=0; u<4; u++) acc[u] += __shfl_xor(acc[u], 32, 64);
  if (ln < 32){                       // phase B: e = mask * exp(score)
    float m = mask[b*SEQ + s0 + s] ? 1.f : 0.f;
    #pragma unroll
    for (int u=0; u<4; u++)
      wf[s*20 + wv*4 + u] = m * __expf(acc[u]);
  }
  __syncthreads();
  if (tid < 16){                      // den partial per head
    float dsum = 0.f;
    #pragma unroll
    for (int ss=0; ss<32; ss++) dsum += wf[ss*20 + tid];
    denp[(sc*BS + b)*NH + tid] = dsum;
  }
  // phase C: weighted pool. wave wv owns d chunk [wv*256, wv*256+256).
  int d = wv*256 + ln*4;
  const float* xbase = x + (size_t)(b*SEQ + s0)*DIM + d;
  float4 a[16];
  #pragma unroll
  for (int q=0; q<16; q++){ a[q].x=0.f; a[q].y=0.f; a[q].z=0.f; a[q].w=0.f; }
#define WACC(Q, WC) \
  a[Q].x += xq[u].x*(WC); a[Q].y += xq[u].y*(WC); a[Q].z += xq[u].z*(WC); a[Q].w += xq[u].w*(WC);
  for (int sb=0; sb<32; sb+=8){
    float4 xq[8];
    #pragma unroll
    for (int u=0; u<8; u++)
      xq[u] = *(const float4*)(xbase + (size_t)(sb+u)*DIM);   // 8 loads in flight
    #pragma unroll
    for (int u=0; u<8; u++){
      float4 w0 = wlds[(sb+u)*5 + 0];
      float4 w1 = wlds[(sb+u)*5 + 1];
      float4 w2 = wlds[(sb+u)*5 + 2];
      float4 w3 = wlds[(sb+u)*5 + 3];
      WACC(0,  w0.x) WACC(1,  w0.y) WACC(2,  w0.z) WACC(3,  w0.w)
      WACC(4,  w1.x) WACC(5,  w1.y) WACC(6,  w1.z) WACC(7,  w1.w)
      WACC(8,  w2.x) WACC(9,  w2.y) WACC(10, w2.z) WACC(11, w2.w)
      WACC(12, w3.x) WACC(13, w3.y) WACC(14, w3.z) WACC(15, w3.w)
    }
  }
#undef WACC
  float* dst = nump + (size_t)sc*(BS*NH*DIM) + (size_t)(b*NH)*DIM + d;
  #pragma unroll
  for (int q=0; q<16; q++)
    *(float4*)(dst + (size_t)q*DIM) = a[q];
}

// ---------------- K3: xw[b,h,d] = sum_sc num / sum_sc den ------------------
__global__ void k_xwred(const float* __restrict__ nump, const float* __restrict__ denp,
                        float* __restrict__ xw){
  int id = blockIdx.x*256 + threadIdx.x;   // 512 blocks -> 131072 ids
  int bh = id >> 10;                        // b*NH + h
  int b = bh >> 4, h = bh & 15;
  float den = 0.f;
  #pragma unroll
  for (int scn=0; scn<32; scn++) den += denp[(scn*BS + b)*NH + h];
  float num = 0.f;
  #pragma unroll
  for (int scn=0; scn<32; scn++) num += nump[(size_t)scn*(BS*NH*DIM) + id];
  xw[id] = num / den;
}

// ---------------- K4: ctx[b,jo] = xw[b,h(jo),:].vw[jo,:] + vb[jo] ----------
__global__ void k_ctx(const float* __restrict__ xw, const float* __restrict__ vw,
                      const float* __restrict__ vb, float* __restrict__ ctx){
  int wv = threadIdx.x >> 6, ln = threadIdx.x & 63;
  int jo = blockIdx.x*4 + wv;
  int h  = jo >> 6;
  float acc[BS] = {0,0,0,0,0,0,0,0};
  #pragma unroll
  for (int i=0; i<4; i++){
    int d = ln*4 + 256*i;
    float4 vv = *(const float4*)(vw + (size_t)jo*DIM + d);
    #pragma unroll
    for (int b=0; b<BS; b++){
      float4 xv = *(const float4*)(xw + (size_t)(b*NH + h)*DIM + d);
      acc[b] += vv.x*xv.x + vv.y*xv.y + vv.z*xv.z + vv.w*xv.w;
    }
  }
  #pragma unroll
  for (int off=32; off>=1; off>>=1){
    #pragma unroll
    for (int b=0; b<BS; b++) acc[b] += __shfl_down(acc[b], off, 64);
  }
  if (ln == 0){
    float bias = vb[jo];
    #pragma unroll
    for (int b=0; b<BS; b++) ctx[b*DIM + jo] = acc[b] + bias;
  }
}

// ---------------- K5: out_row[b,i] = ctx[b,:].ow[i,:] + ob[i] ----------------
__global__ void k_outrow(const float* __restrict__ ctx, const float* __restrict__ ow,
                         const float* __restrict__ ob, float* __restrict__ outr){
  int wv = threadIdx.x >> 6, ln = threadIdx.x & 63;
  int io = blockIdx.x*4 + wv;
  float acc[BS] = {0,0,0,0,0,0,0,0};
  #pragma unroll
  for (int i=0; i<4; i++){
    int d = ln*4 + 256*i;
    float4 wt = *(const float4*)(ow + (size_t)io*DIM + d);
    #pragma unroll
    for (int b=0; b<BS; b++){
      float4 cv = *(const float4*)(ctx + b*DIM + d);
      acc[b] += wt.x*cv.x + wt.y*cv.y + wt.z*cv.z + wt.w*cv.w;
    }
  }
  #pragma unroll
  for (int off=32; off>=1; off>>=1){
    #pragma unroll
    for (int b=0; b<BS; b++) acc[b] += __shfl_down(acc[b], off, 64);
  }
  if (ln == 0){
    float bias = ob[io];
    #pragma unroll
    for (int b=0; b<BS; b++) outr[b*DIM + io] = acc[b] + bias;
  }
}

// ---------------- K6: out[b,s,:] = LN(out_row[b]+x[b,s,:])*g + beta ---------
__global__ void k_ln(const float* __restrict__ x, const float* __restrict__ outr,
                     const float* __restrict__ g, const float* __restrict__ bt,
                     float* __restrict__ out){
  int row = blockIdx.x;
  int b = row >> 10;
  size_t base = (size_t)row * DIM;
  int tid = threadIdx.x;
  float4 xv = ((const float4*)(x + base))[tid];
  float4 ov = ((const float4*)(outr + (size_t)b*DIM))[tid];
  float4 h;
  h.x = xv.x + ov.x; h.y = xv.y + ov.y; h.z = xv.z + ov.z; h.w = xv.w + ov.w;
  float s  = h.x + h.y + h.z + h.w;
  float s2 = h.x*h.x + h.y*h.y + h.z*h.z + h.w*h.w;
  #pragma unroll
  for (int off=32; off>=1; off>>=1){
    s  += __shfl_xor(s,  off, 64);
    s2 += __shfl_xor(s2, off, 64);
  }
  __shared__ float r1[4], r2[4];
  int wv = tid >> 6, ln = tid & 63;
  if (ln == 0){ r1[wv] = s; r2[wv] = s2; }
  __syncthreads();
  s  = r1[0] + r1[1] + r1[2] + r1[3];
  s2 = r2[0] + r2[1] + r2[2] + r2[3];
  float mu   = s  * (1.f/1024.f);
  float var  = s2 * (1.f/1024.f) - mu*mu;
  float rstd = rsqrtf(var + 1e-12f);
  float4 gv = ((const float4*)g)[tid];
  float4 bv = ((const float4*)bt)[tid];
  float4 y;
  y.x = (h.x - mu)*rstd*gv.x + bv.x;
  y.y = (h.y - mu)*rstd*gv.y + bv.y;
  y.z = (h.z - mu)*rstd*gv.z + bv.z;
  y.w = (h.w - mu)*rstd*gv.w + bv.w;
  ((float4*)(out + base))[tid] = y;
}

extern "C" void kernel_launch(void* const* d_in, const int* in_sizes, int n_in,
                              void* d_out, int out_size, void* d_ws, size_t ws_size,
                              hipStream_t stream) {
  const float* x    = (const float*)d_in[0];
  const float* xnb  = (const float*)d_in[1];
  const int*   mask = (const int*  )d_in[2];
  const float* nm   = (const float*)d_in[3];
  const float* qw   = (const float*)d_in[4];
  const float* qb   = (const float*)d_in[5];
  const float* kw   = (const float*)d_in[6];
  // d_in[7] = kb: softmax-invariant constant, unused
  const float* vw   = (const float*)d_in[8];
  const float* vb   = (const float*)d_in[9];
  const float* ow   = (const float*)d_in[10];
  const float* ob   = (const float*)d_in[11];
  const float* lng  = (const float*)d_in[12];
  const float* lnb  = (const float*)d_in[13];
  float* out = (float*)d_out;

  float* ws   = (float*)d_ws;              // ~17.9 MB of ~256 MB ws
  float* p    = ws + OF_P;
  float* nump = ws + OF_NUMP;              // 32 s-chunk slabs
  float* denp = ws + OF_DENP;              // 32 x 128
  float* xw   = ws + OF_XW;
  float* ctx  = ws + OF_CTX;
  float* outr = ws + OF_OUTR;

  k_prep  <<<128,             256, 0, stream>>>(xnb, nm, qw, qb, kw, p);
  k_swp   <<<dim3(BS,32),     256, 0, stream>>>(x, p, mask, nump, denp);
  k_xwred <<<512,             256, 0, stream>>>(nump, denp, xw);
  k_ctx   <<<256,             256, 0, stream>>>(xw, vw, vb, ctx);
  k_outrow<<<256,             256, 0, stream>>>(ctx, ow, ob, outr);
  k_ln    <<<BS*SEQ,          256, 0, stream>>>(x, outr, lng, lnb, out);
}

// Round 3
// 173.090 us; speedup vs baseline: 1.0514x; 1.0514x over previous
//
#include <hip/hip_runtime.h>
#include <hip/hip_bf16.h>

// NeighborAttention on MI355X. fp32 in/out, int32 mask.
// KEY INSIGHT (R0): query = broadcast of masked neighbor-mean -> all seq
// positions share one query per (b,h). Attention collapses to GEMV-scale work.
// R6/R7 POST-MORTEM: device-wide software barriers cost ~40us EACH on MI355X.
// R9 POST-MORTEM (recorded): fused k_swp @256 threads spilled (VGPR_Count=64
// vs >=96 live: a[16]+xq[8] float4) -> 14 MB scratch write traffic, 1 wave/SIMD,
// VALUBusy 0.19%, 142.8us. Fusion theory OK, register budget was not.
// R10: k_swp rebuilt: 1024-thread blocks (16 waves, 4/SIMD), phase A with p in
// REGISTERS (4 float4/lane) + x read direct from global (row-contiguous,
// L1/L2-hot across hg-waves) + shfl_xor butterfly to finish the 1024-d dot;
// phase C 4-head accumulators (16 VGPRs). No LDS x/p staging (LDS = 2.5 KB
// e-weights only). __launch_bounds__(1024,4) caps VGPR at 128; est live
// ~80-110 -> no spills.
// R11 (this round): R10 bench never ran (GPU acquisition timeout) -> resubmit
// R10 UNCHANGED to measure the spill-fix hypothesis before stacking changes.

#define DIM  1024
#define NH   16
#define HD   64
#define BS   8
#define SEQ  1024
#define NNB  50

// workspace offsets (floats), all 16B-aligned
#define OF_P     16
#define OF_NUMP  131088
#define OF_DENP  4325392
#define OF_XW    4329488
#define OF_CTX   4460560
#define OF_OUTR  4468752

// ---------------- K1: fused neighbor-pool + q + p, one block per (h,b) -------
__global__ void k_prep(const float* __restrict__ xnb, const float* __restrict__ nm,
                       const float* __restrict__ qw, const float* __restrict__ qb,
                       const float* __restrict__ kw, float* __restrict__ p){
  int h = blockIdx.x & 15, b = blockIdx.x >> 4;
  int tid = threadIdx.x, wv = tid >> 6, ln = tid & 63;
  __shared__ float xnl[1024];
  __shared__ float qp[256];
  __shared__ float ql[64];
  {  // masked neighbor mean
    int d = tid*4;
    float4 acc = {0,0,0,0}; float wsum = 0.f;
    #pragma unroll 10
    for (int n=0; n<NNB; n++){
      float w = nm[b*NNB + n];
      float4 v = *(const float4*)(xnb + (size_t)(b*NNB + n)*DIM + d);
      acc.x += w*v.x; acc.y += w*v.y; acc.z += w*v.z; acc.w += w*v.w;
      wsum += w;
    }
    float inv = 1.f/wsum;
    acc.x*=inv; acc.y*=inv; acc.z*=inv; acc.w*=inv;
    *(float4*)(xnl + d) = acc;
  }
  __syncthreads();
  {  // q partial: lane ln -> row h*64+ln of qw, wave wv -> 256-d chunk
    const float* qrow = qw + (size_t)(h*HD + ln)*DIM + wv*256;
    const float* xrow = xnl + wv*256;
    float part = 0.f;
    #pragma unroll 16
    for (int i=0; i<64; i++){
      float4 a = *(const float4*)(qrow + i*4);
      float4 c = *(const float4*)(xrow + i*4);
      part += a.x*c.x + a.y*c.y + a.z*c.z + a.w*c.w;
    }
    qp[wv*64 + ln] = part;
  }
  __syncthreads();
  if (wv == 0){
    float qv = qp[ln] + qp[64+ln] + qp[128+ln] + qp[192+ln];
    ql[ln] = (qv + qb[h*HD + ln]) * 0.125f;
  }
  __syncthreads();
  {  // p[b,h,d] = sum_j ql[j]*kw[h*64+j,d]
    int d = tid*4;
    float4 acc = {0,0,0,0};
    #pragma unroll 8
    for (int j=0; j<HD; j++){
      float qj = ql[j];
      float4 kv = *(const float4*)(kw + (size_t)(h*HD + j)*DIM + d);
      acc.x += qj*kv.x; acc.y += qj*kv.y; acc.z += qj*kv.z; acc.w += qj*kv.w;
    }
    *(float4*)(p + (size_t)(b*NH + h)*DIM + d) = acc;
  }
}

// ---------------- K2: fused scores + exp + weighted pool (v2) ---------------
// grid (8 b, 32 sc), block 1024 = 16 waves. Block: 32 seq rows x 16 heads.
// Phase A: wave wv -> (hg = wv&3 head-group, sq = wv>>2 s-quarter of 8 rows).
//   Lane ln covers d = kc*256 + ln*4. p for 4 heads in registers (4 float4),
//   x read direct from global (1 KB contiguous per row per wave; 4 hg-waves
//   share rows -> L1-hot). acc[8][4] partials; shfl_xor butterfly over 64
//   lanes completes the 1024-d dot; lane 0 writes raw scores to wf.
// Phase B: 512 threads apply mask*exp in-place; den partial per head.
// Phase C: wave wv -> (hg2 = wv>>2, dc = wv&3); lane d = dc*256+ln*4; 4-head
//   float4 accumulators; x re-read (L1/L2-hot); writes nump slab sc.
__global__ __launch_bounds__(1024, 4)
void k_swp(const float* __restrict__ x, const float* __restrict__ p,
           const int* __restrict__ mask,
           float* __restrict__ nump, float* __restrict__ denp){
  int b = blockIdx.x, sc = blockIdx.y;
  int s0 = sc * 32;
  int tid = threadIdx.x, wv = tid >> 6, ln = tid & 63;
  __shared__ float wf[32*20];          // [s][h] stride-20, 2.5 KB

  int hg = wv & 3, sq = wv >> 2;
  float acc[8][4];
  #pragma unroll
  for (int i=0; i<8; i++){ acc[i][0]=0.f; acc[i][1]=0.f; acc[i][2]=0.f; acc[i][3]=0.f; }

  #pragma unroll 1
  for (int kc=0; kc<4; kc++){
    int d = kc*256 + ln*4;
    const float* pb = p + (size_t)(b*NH + hg*4)*DIM + d;
    float4 pr0 = *(const float4*)(pb);
    float4 pr1 = *(const float4*)(pb +   (size_t)DIM);
    float4 pr2 = *(const float4*)(pb + 2*(size_t)DIM);
    float4 pr3 = *(const float4*)(pb + 3*(size_t)DIM);
    const float* xb = x + (size_t)(b*SEQ + s0 + sq*8)*DIM + d;
    #pragma unroll
    for (int sb=0; sb<8; sb+=4){
      float4 xr[4];
      #pragma unroll
      for (int u=0; u<4; u++)
        xr[u] = *(const float4*)(xb + (size_t)(sb+u)*DIM);
      #pragma unroll
      for (int u=0; u<4; u++){
        acc[sb+u][0] += xr[u].x*pr0.x + xr[u].y*pr0.y + xr[u].z*pr0.z + xr[u].w*pr0.w;
        acc[sb+u][1] += xr[u].x*pr1.x + xr[u].y*pr1.y + xr[u].z*pr1.z + xr[u].w*pr1.w;
        acc[sb+u][2] += xr[u].x*pr2.x + xr[u].y*pr2.y + xr[u].z*pr2.z + xr[u].w*pr2.w;
        acc[sb+u][3] += xr[u].x*pr3.x + xr[u].y*pr3.y + xr[u].z*pr3.z + xr[u].w*pr3.w;
      }
    }
  }
  // butterfly: complete each (s,h) dot across the 64 lanes' d-slices
  #pragma unroll
  for (int off=1; off<64; off<<=1){
    #pragma unroll
    for (int si=0; si<8; si++){
      acc[si][0] += __shfl_xor(acc[si][0], off, 64);
      acc[si][1] += __shfl_xor(acc[si][1], off, 64);
      acc[si][2] += __shfl_xor(acc[si][2], off, 64);
      acc[si][3] += __shfl_xor(acc[si][3], off, 64);
    }
  }
  if (ln == 0){
    #pragma unroll
    for (int si=0; si<8; si++){
      float4 v; v.x = acc[si][0]; v.y = acc[si][1]; v.z = acc[si][2]; v.w = acc[si][3];
      *(float4*)(wf + (sq*8 + si)*20 + hg*4) = v;
    }
  }
  __syncthreads();
  if (tid < 512){                      // phase B: e = mask * exp(score), in place
    int s = tid >> 4, h = tid & 15;
    float sv = wf[s*20 + h];
    wf[s*20 + h] = mask[b*SEQ + s0 + s] ? __expf(sv) : 0.f;
  }
  __syncthreads();
  if (tid < 16){                       // den partial per head
    float dsum = 0.f;
    #pragma unroll
    for (int ss=0; ss<32; ss++) dsum += wf[ss*20 + tid];
    denp[(sc*BS + b)*NH + tid] = dsum;
  }
  // phase C: weighted pool. wave wv -> heads hg2*4..+3, d chunk dc*256..+255.
  int hg2 = wv >> 2, dc = wv & 3;
  int d = dc*256 + ln*4;
  const float* xbase = x + (size_t)(b*SEQ + s0)*DIM + d;
  float4 a0={0,0,0,0}, a1={0,0,0,0}, a2={0,0,0,0}, a3={0,0,0,0};
  #pragma unroll 2
  for (int sb=0; sb<32; sb+=4){
    float4 xq[4];
    #pragma unroll
    for (int u=0; u<4; u++)
      xq[u] = *(const float4*)(xbase + (size_t)(sb+u)*DIM);
    #pragma unroll
    for (int u=0; u<4; u++){
      float4 w = *(const float4*)(wf + (sb+u)*20 + hg2*4);   // wave-uniform bcast
      a0.x += xq[u].x*w.x; a0.y += xq[u].y*w.x; a0.z += xq[u].z*w.x; a0.w += xq[u].w*w.x;
      a1.x += xq[u].x*w.y; a1.y += xq[u].y*w.y; a1.z += xq[u].z*w.y; a1.w += xq[u].w*w.y;
      a2.x += xq[u].x*w.z; a2.y += xq[u].y*w.z; a2.z += xq[u].z*w.z; a2.w += xq[u].w*w.z;
      a3.x += xq[u].x*w.w; a3.y += xq[u].y*w.w; a3.z += xq[u].z*w.w; a3.w += xq[u].w*w.w;
    }
  }
  float* dst = nump + (size_t)sc*(BS*NH*DIM) + (size_t)(b*NH + hg2*4)*DIM + d;
  *(float4*)(dst                 ) = a0;
  *(float4*)(dst +   (size_t)DIM ) = a1;
  *(float4*)(dst + 2*(size_t)DIM ) = a2;
  *(float4*)(dst + 3*(size_t)DIM ) = a3;
}

// ---------------- K3: xw[b,h,d] = sum_sc num / sum_sc den ------------------
__global__ void k_xwred(const float* __restrict__ nump, const float* __restrict__ denp,
                        float* __restrict__ xw){
  int id = blockIdx.x*256 + threadIdx.x;   // 512 blocks -> 131072 ids
  int bh = id >> 10;                        // b*NH + h
  int b = bh >> 4, h = bh & 15;
  float den = 0.f;
  #pragma unroll
  for (int scn=0; scn<32; scn++) den += denp[(scn*BS + b)*NH + h];
  float num = 0.f;
  #pragma unroll
  for (int scn=0; scn<32; scn++) num += nump[(size_t)scn*(BS*NH*DIM) + id];
  xw[id] = num / den;
}

// ---------------- K4: ctx[b,jo] = xw[b,h(jo),:].vw[jo,:] + vb[jo] ----------
__global__ void k_ctx(const float* __restrict__ xw, const float* __restrict__ vw,
                      const float* __restrict__ vb, float* __restrict__ ctx){
  int wv = threadIdx.x >> 6, ln = threadIdx.x & 63;
  int jo = blockIdx.x*4 + wv;
  int h  = jo >> 6;
  float acc[BS] = {0,0,0,0,0,0,0,0};
  #pragma unroll
  for (int i=0; i<4; i++){
    int d = ln*4 + 256*i;
    float4 vv = *(const float4*)(vw + (size_t)jo*DIM + d);
    #pragma unroll
    for (int b=0; b<BS; b++){
      float4 xv = *(const float4*)(xw + (size_t)(b*NH + h)*DIM + d);
      acc[b] += vv.x*xv.x + vv.y*xv.y + vv.z*xv.z + vv.w*xv.w;
    }
  }
  #pragma unroll
  for (int off=32; off>=1; off>>=1){
    #pragma unroll
    for (int b=0; b<BS; b++) acc[b] += __shfl_down(acc[b], off, 64);
  }
  if (ln == 0){
    float bias = vb[jo];
    #pragma unroll
    for (int b=0; b<BS; b++) ctx[b*DIM + jo] = acc[b] + bias;
  }
}

// ---------------- K5: out_row[b,i] = ctx[b,:].ow[i,:] + ob[i] ----------------
__global__ void k_outrow(const float* __restrict__ ctx, const float* __restrict__ ow,
                         const float* __restrict__ ob, float* __restrict__ outr){
  int wv = threadIdx.x >> 6, ln = threadIdx.x & 63;
  int io = blockIdx.x*4 + wv;
  float acc[BS] = {0,0,0,0,0,0,0,0};
  #pragma unroll
  for (int i=0; i<4; i++){
    int d = ln*4 + 256*i;
    float4 wt = *(const float4*)(ow + (size_t)io*DIM + d);
    #pragma unroll
    for (int b=0; b<BS; b++){
      float4 cv = *(const float4*)(ctx + b*DIM + d);
      acc[b] += wt.x*cv.x + wt.y*cv.y + wt.z*cv.z + wt.w*cv.w;
    }
  }
  #pragma unroll
  for (int off=32; off>=1; off>>=1){
    #pragma unroll
    for (int b=0; b<BS; b++) acc[b] += __shfl_down(acc[b], off, 64);
  }
  if (ln == 0){
    float bias = ob[io];
    #pragma unroll
    for (int b=0; b<BS; b++) outr[b*DIM + io] = acc[b] + bias;
  }
}

// ---------------- K6: out[b,s,:] = LN(out_row[b]+x[b,s,:])*g + beta ---------
__global__ void k_ln(const float* __restrict__ x, const float* __restrict__ outr,
                     const float* __restrict__ g, const float* __restrict__ bt,
                     float* __restrict__ out){
  int row = blockIdx.x;
  int b = row >> 10;
  size_t base = (size_t)row * DIM;
  int tid = threadIdx.x;
  float4 xv = ((const float4*)(x + base))[tid];
  float4 ov = ((const float4*)(outr + (size_t)b*DIM))[tid];
  float4 h;
  h.x = xv.x + ov.x; h.y = xv.y + ov.y; h.z = xv.z + ov.z; h.w = xv.w + ov.w;
  float s  = h.x + h.y + h.z + h.w;
  float s2 = h.x*h.x + h.y*h.y + h.z*h.z + h.w*h.w;
  #pragma unroll
  for (int off=32; off>=1; off>>=1){
    s  += __shfl_xor(s,  off, 64);
    s2 += __shfl_xor(s2, off, 64);
  }
  __shared__ float r1[4], r2[4];
  int wv = tid >> 6, ln = tid & 63;
  if (ln == 0){ r1[wv] = s; r2[wv] = s2; }
  __syncthreads();
  s  = r1[0] + r1[1] + r1[2] + r1[3];
  s2 = r2[0] + r2[1] + r2[2] + r2[3];
  float mu   = s  * (1.f/1024.f);
  float var  = s2 * (1.f/1024.f) - mu*mu;
  float rstd = rsqrtf(var + 1e-12f);
  float4 gv = ((const float4*)g)[tid];
  float4 bv = ((const float4*)bt)[tid];
  float4 y;
  y.x = (h.x - mu)*rstd*gv.x + bv.x;
  y.y = (h.y - mu)*rstd*gv.y + bv.y;
  y.z = (h.z - mu)*rstd*gv.z + bv.z;
  y.w = (h.w - mu)*rstd*gv.w + bv.w;
  ((float4*)(out + base))[tid] = y;
}

extern "C" void kernel_launch(void* const* d_in, const int* in_sizes, int n_in,
                              void* d_out, int out_size, void* d_ws, size_t ws_size,
                              hipStream_t stream) {
  const float* x    = (const float*)d_in[0];
  const float* xnb  = (const float*)d_in[1];
  const int*   mask = (const int*  )d_in[2];
  const float* nm   = (const float*)d_in[3];
  const float* qw   = (const float*)d_in[4];
  const float* qb   = (const float*)d_in[5];
  const float* kw   = (const float*)d_in[6];
  // d_in[7] = kb: softmax-invariant constant, unused
  const float* vw   = (const float*)d_in[8];
  const float* vb   = (const float*)d_in[9];
  const float* ow   = (const float*)d_in[10];
  const float* ob   = (const float*)d_in[11];
  const float* lng  = (const float*)d_in[12];
  const float* lnb  = (const float*)d_in[13];
  float* out = (float*)d_out;

  float* ws   = (float*)d_ws;              // ~17.9 MB of ~256 MB ws
  float* p    = ws + OF_P;
  float* nump = ws + OF_NUMP;              // 32 s-chunk slabs
  float* denp = ws + OF_DENP;              // 32 x 128
  float* xw   = ws + OF_XW;
  float* ctx  = ws + OF_CTX;
  float* outr = ws + OF_OUTR;

  k_prep  <<<128,             256,  0, stream>>>(xnb, nm, qw, qb, kw, p);
  k_swp   <<<dim3(BS,32),     1024, 0, stream>>>(x, p, mask, nump, denp);
  k_xwred <<<512,             256,  0, stream>>>(nump, denp, xw);
  k_ctx   <<<256,             256,  0, stream>>>(xw, vw, vb, ctx);
  k_outrow<<<256,             256,  0, stream>>>(ctx, ow, ob, outr);
  k_ln    <<<BS*SEQ,          256,  0, stream>>>(x, outr, lng, lnb, out);
}